// Round 1
// baseline (1031.684 us; speedup 1.0000x reference)
//
#include <hip/hip_runtime.h>

// ---------------------------------------------------------------------------
// LocalGlobalBlock on MI355X.
// Stages:
//   k_prep : fold BN1/BN2 + biases into per-channel (alpha,beta); gpw -> bf16
//   k_wds  : ds_w [512][256][3][3] fp32 -> wds bf16 [oc][khw*256+ic] (k-reordered)
//   k_pool : mean over HxW of local half -> pooled[16][128]
//   k_kgen : relu(pooled @ W_kg^T) -> kgen[16][128][9]
//   k_xt   : x NCHW fp32 -> xT NHWC bf16 (stored in d_out as scratch; exact fit)
//   k_dwc  : fused local per-sample dw-conv (-> comb ch 0..127) and global
//            dilated dw-conv (-> tbuf), both reading channel-minor xT
//   k_pw   : 1x1 conv as MFMA GEMM + BN1 + ReLU -> comb ch 128..255
//   k_ds   : downsample 3x3 stride2 as implicit MFMA GEMM + BN2 + ReLU -> d_out
//
// comb layout: [b][h][parity][w2][ch] bf16, w = 2*w2+parity. For fixed (kh,kw)
// the stride-2 column gather becomes a contiguous w2 range (channel-minor), so
// the k_ds B-tile staging is 16B vector loads.
// ---------------------------------------------------------------------------

#define DEVI static __device__ __forceinline__

using bf16x8 = __attribute__((ext_vector_type(8))) short;  // 8 bf16 (4 VGPRs)
using f32x4  = __attribute__((ext_vector_type(4))) float;  // MFMA accumulator
typedef unsigned short ushort_t;

constexpr int Bn = 16, MID = 128, CHN = 256, Hh = 112, Wn = 112;
constexpr int OHn = 56, OWn = 56, OCn = 512;
constexpr int HW  = Hh * Wn;        // 12544
constexpr int NPX = Bn * HW;        // 200704
constexpr int KDS = CHN * 9;        // 2304
constexpr float EPSf = 1e-5f;

DEVI ushort_t f2b(float f) {  // fp32 -> bf16 RNE (finite data only)
    unsigned u = __float_as_uint(f);
    return (ushort_t)((u + 0x7FFFu + ((u >> 16) & 1u)) >> 16);
}
DEVI float b2f(ushort_t s) { return __uint_as_float(((unsigned)s) << 16); }

// ------------------------- k_prep ------------------------------------------
__global__ __launch_bounds__(256) void k_prep(
        const float* __restrict__ gpw_w, const float* __restrict__ gpw_b,
        const float* __restrict__ bn1g, const float* __restrict__ bn1b,
        const float* __restrict__ bn1m, const float* __restrict__ bn1v,
        const float* __restrict__ dsb,
        const float* __restrict__ bn2g, const float* __restrict__ bn2b,
        const float* __restrict__ bn2m, const float* __restrict__ bn2v,
        ushort_t* __restrict__ gpwbf,
        float* __restrict__ a1, float* __restrict__ b1,
        float* __restrict__ a2, float* __restrict__ b2) {
    int i = blockIdx.x * 256 + threadIdx.x;
    if (i < MID * MID) gpwbf[i] = f2b(gpw_w[i]);
    if (i < OCn) {
        float inv = bn2g[i] / sqrtf(bn2v[i] + EPSf);
        a2[i] = inv;
        b2[i] = bn2b[i] + (dsb[i] - bn2m[i]) * inv;   // folds ds bias + BN2
    }
    if (i < MID) {
        float inv = bn1g[i] / sqrtf(bn1v[i] + EPSf);
        a1[i] = inv;
        b1[i] = bn1b[i] + (gpw_b[i] - bn1m[i]) * inv; // folds 1x1 bias + BN1
    }
}

// ------------------------- k_wds -------------------------------------------
// wds[oc][khw*256 + ic] = bf16(ds_w[oc][ic][kh][kw]),  khw = kh*3+kw
__global__ __launch_bounds__(256) void k_wds(const float* __restrict__ dsw,
                                             ushort_t* __restrict__ wds) {
    int idx = blockIdx.x * 256 + threadIdx.x;          // < 512*2304
    int o = idx / KDS, k = idx % KDS;
    int khw = k / CHN, ic = k % CHN;
    wds[idx] = f2b(dsw[(size_t)(o * CHN + ic) * 9 + khw]);
}

// ------------------------- k_pool ------------------------------------------
__global__ __launch_bounds__(256) void k_pool(const float* __restrict__ x,
                                              float* __restrict__ pooled) {
    __shared__ float red[256];
    int bc = blockIdx.x;                 // b*128 + c (local half only)
    int b = bc >> 7, c = bc & 127;
    const float* p = x + (size_t)(b * CHN + c) * HW;
    float s = 0.f;
    for (int i = threadIdx.x; i < HW; i += 256) s += p[i];
    red[threadIdx.x] = s;
    __syncthreads();
    for (int st = 128; st > 0; st >>= 1) {
        if ((int)threadIdx.x < st) red[threadIdx.x] += red[threadIdx.x + st];
        __syncthreads();
    }
    if (threadIdx.x == 0) pooled[bc] = red[0] * (1.f / HW);
}

// ------------------------- k_kgen ------------------------------------------
__global__ __launch_bounds__(256) void k_kgen(const float* __restrict__ pooled,
                                              const float* __restrict__ wkg,
                                              float* __restrict__ kgen) {
    int idx = blockIdx.x * 256 + threadIdx.x;          // < 16*1152
    int b = idx / 1152, j = idx % 1152;
    const float* pr = pooled + b * MID;
    const float* wr = wkg + (size_t)j * MID;
    float s = 0.f;
#pragma unroll 8
    for (int i = 0; i < MID; i++) s += pr[i] * wr[i];
    kgen[idx] = fmaxf(s, 0.f);
}

// ------------------------- k_xt --------------------------------------------
// x[b][ch][h][w] fp32 -> xT[b][h][w][ch] bf16, one block per (b,h) row.
__global__ __launch_bounds__(256) void k_xt(const float* __restrict__ x,
                                            ushort_t* __restrict__ xT) {
    __shared__ ushort_t tile[Wn * 264];  // [w][ch], pad 264 breaks conflicts
    int bh = blockIdx.x;
    int b = bh / Hh, h = bh % Hh;
    const float* xp = x + ((size_t)b * CHN * Hh + h) * Wn; // + ch*HW + w
    for (int idx = threadIdx.x; idx < Wn * CHN; idx += 256) {
        int ch = idx / Wn, w = idx % Wn;               // lanes -> w (coalesced)
        tile[w * 264 + ch] = f2b(xp[(size_t)ch * HW + w]);
    }
    __syncthreads();
    int4* dst = (int4*)(xT + (size_t)bh * Wn * CHN);   // contiguous slab
    for (int q = threadIdx.x; q < Wn * CHN / 8; q += 256) {
        int w = q >> 5, c0 = (q & 31) << 3;
        dst[q] = *(const int4*)(tile + w * 264 + c0);
    }
}

// ------------------------- k_dwc -------------------------------------------
// Fused local per-sample depthwise (pad1) + global dilated-2 depthwise (pad2).
// 2 pixels per block, 128 channel-lanes each (coalesced channel-minor I/O).
__global__ __launch_bounds__(256) void k_dwc(
        const ushort_t* __restrict__ xT, const float* __restrict__ kgen,
        const float* __restrict__ gdw_w, const float* __restrict__ gdw_b,
        ushort_t* __restrict__ comb, ushort_t* __restrict__ tbuf) {
    int t = threadIdx.x;
    int c = t & 127, pxi = t >> 7;
    int px = blockIdx.x * 2 + pxi;
    int b = px / HW, rem = px % HW, h = rem / Wn, w = rem % Wn;
    const ushort_t* xb = xT + (size_t)b * HW * CHN;
    float kk[9], gw[9];
#pragma unroll
    for (int tp = 0; tp < 9; tp++) {
        kk[tp] = kgen[b * 1152 + c * 9 + tp];
        gw[tp] = gdw_w[c * 9 + tp];
    }
    float accl = 0.f, accg = 0.f;
#pragma unroll
    for (int dh = -1; dh <= 1; dh++) {
#pragma unroll
        for (int dw = -1; dw <= 1; dw++) {
            int tp = (dh + 1) * 3 + (dw + 1);
            int h1 = h + dh, w1 = w + dw;
            if ((unsigned)h1 < (unsigned)Hh && (unsigned)w1 < (unsigned)Wn)
                accl += kk[tp] * b2f(xb[(size_t)(h1 * Wn + w1) * CHN + c]);
            int h2 = h + 2 * dh, w2 = w + 2 * dw;
            if ((unsigned)h2 < (unsigned)Hh && (unsigned)w2 < (unsigned)Wn)
                accg += gw[tp] * b2f(xb[(size_t)(h2 * Wn + w2) * CHN + MID + c]);
        }
    }
    accg += gdw_b[c];
    comb[(((size_t)(b * Hh + h) * 2 + (w & 1)) * 56 + (w >> 1)) * CHN + c] = f2b(accl);
    tbuf[(size_t)px * MID + c] = f2b(accg);
}

// ------------------------- k_pw --------------------------------------------
// 1x1 conv: D[px][oc2] = sum_ci t[px][ci] * gpw[oc2][ci]; + BN1 + ReLU.
// MFMA 16x16x32 bf16, operands straight from global (both K-minor).
__global__ __launch_bounds__(256) void k_pw(
        const ushort_t* __restrict__ tbuf, const ushort_t* __restrict__ gpwbf,
        const float* __restrict__ a1, const float* __restrict__ b1,
        ushort_t* __restrict__ comb) {
    int t = threadIdx.x, lane = t & 63, wave = t >> 6;
    int px0 = blockIdx.x * 64 + wave * 16;
    int mrow = lane & 15, quad = lane >> 4;
    const short* tb = (const short*)tbuf;
    const short* gw = (const short*)gpwbf;
    f32x4 acc[8] = {};
#pragma unroll
    for (int kc = 0; kc < 4; kc++) {
        bf16x8 a = *(const bf16x8*)(tb + (size_t)(px0 + mrow) * MID + kc * 32 + quad * 8);
#pragma unroll
        for (int n = 0; n < 8; n++) {
            bf16x8 bf = *(const bf16x8*)(gw + (size_t)(n * 16 + mrow) * MID + kc * 32 + quad * 8);
            acc[n] = __builtin_amdgcn_mfma_f32_16x16x32_bf16(a, bf, acc[n], 0, 0, 0);
        }
    }
#pragma unroll
    for (int n = 0; n < 8; n++) {
        int oc2 = n * 16 + mrow;                        // D col = lane&15
        float al = a1[oc2], be = b1[oc2];
#pragma unroll
        for (int r = 0; r < 4; r++) {                   // D row = quad*4+reg
            int px = px0 + quad * 4 + r;
            float v = fmaxf(acc[n][r] * al + be, 0.f);
            int b = px / HW, rem = px % HW, h = rem / Wn, w = rem % Wn;
            comb[(((size_t)(b * Hh + h) * 2 + (w & 1)) * 56 + (w >> 1)) * CHN + MID + oc2] = f2b(v);
        }
    }
}

// ------------------------- k_ds --------------------------------------------
// Downsample 3x3 stride2 pad1 as implicit GEMM.
// Block tile: 128 oc x 64 ow (one (b,oh) output row, ow>=56 masked).
// K = 9*256, BK = 32 (fixed (kh,kw), 32 input channels per step).
__global__ __launch_bounds__(256) void k_ds(
        const ushort_t* __restrict__ comb, const ushort_t* __restrict__ wds,
        const float* __restrict__ a2, const float* __restrict__ b2,
        float* __restrict__ out) {
    __shared__ ushort_t lA[128 * 40];   // [oc][32k], stride 40 spreads banks
    __shared__ ushort_t lB[64 * 40];    // [ow][32k]
    int t = threadIdx.x, lane = t & 63, wave = t >> 6;
    int oc0 = blockIdx.x * 128;         // M-tile (x-fastest: share B in L2)
    int nt = blockIdx.y;                // (b, oh)
    int bb = nt / OHn, oh = nt % OHn;
    int mrow = lane & 15, quad = lane >> 4;
    const short* cb = (const short*)comb;
    const short* wd = (const short*)wds;
    int arow = t >> 2, akg = (t & 3) * 8;   // A staging: rows arow, arow+64
    int bow  = t >> 2, bkg = (t & 3) * 8;   // B staging: one ow per 4 lanes

    f32x4 acc[2][4] = {};
    for (int kt = 0; kt < 72; kt++) {
        int khw = kt >> 3, icc = kt & 7;
        int kh = khw / 3, kw = khw % 3;
        // --- gather next tiles into registers ---
        const short* wsrc = wd + (size_t)(oc0 + arow) * KDS + khw * 256 + icc * 32 + akg;
        int4 av0 = *(const int4*)wsrc;
        int4 av1 = *(const int4*)(wsrc + (size_t)64 * KDS);
        int r = 2 * oh - 1 + kh;                 // input row; -1 => zero pad
        int off = (kw == 0) ? -1 : 0;
        int p   = (kw == 1) ? 0 : 1;             // input col = 2*w2 + p
        int w2 = bow + off;
        int4 bv = {0, 0, 0, 0};
        if (r >= 0 && w2 >= 0 && w2 < 56)
            bv = *(const int4*)(cb + (((size_t)(bb * Hh + r) * 2 + p) * 56 + w2) * CHN
                                  + icc * 32 + bkg);
        // --- stage ---
        __syncthreads();
        *(int4*)(lA + arow * 40 + akg) = av0;
        *(int4*)(lA + (arow + 64) * 40 + akg) = av1;
        *(int4*)(lB + bow * 40 + bkg) = bv;
        __syncthreads();
        // --- MFMA: each wave 32oc x 64ow ---
        bf16x8 afr[2], bfr[4];
#pragma unroll
        for (int s = 0; s < 2; s++)
            afr[s] = *(const bf16x8*)(lA + (wave * 32 + s * 16 + mrow) * 40 + quad * 8);
#pragma unroll
        for (int n = 0; n < 4; n++)
            bfr[n] = *(const bf16x8*)(lB + (n * 16 + mrow) * 40 + quad * 8);
#pragma unroll
        for (int s = 0; s < 2; s++)
#pragma unroll
            for (int n = 0; n < 4; n++)
                acc[s][n] = __builtin_amdgcn_mfma_f32_16x16x32_bf16(afr[s], bfr[n], acc[s][n], 0, 0, 0);
    }
    // --- epilogue: BN2 + ReLU, mask padded ow ---
#pragma unroll
    for (int s = 0; s < 2; s++) {
#pragma unroll
        for (int r4 = 0; r4 < 4; r4++) {
            int oc = oc0 + wave * 32 + s * 16 + quad * 4 + r4;
            float al = a2[oc], be = b2[oc];
#pragma unroll
            for (int n = 0; n < 4; n++) {
                int ow = n * 16 + mrow;
                if (ow < OWn) {
                    float v = fmaxf(acc[s][n][r4] * al + be, 0.f);
                    out[(((size_t)(bb * OCn + oc) * OHn + oh)) * OWn + ow] = v;
                }
            }
        }
    }
}

// ------------------------- launch ------------------------------------------
extern "C" void kernel_launch(void* const* d_in, const int* in_sizes, int n_in,
                              void* d_out, int out_size, void* d_ws, size_t ws_size,
                              hipStream_t stream) {
    const float* x     = (const float*)d_in[0];
    const float* wkg   = (const float*)d_in[1];
    const float* gdw_w = (const float*)d_in[2];
    const float* gdw_b = (const float*)d_in[3];
    const float* gpw_w = (const float*)d_in[4];
    const float* gpw_b = (const float*)d_in[5];
    const float* bn1g  = (const float*)d_in[6];
    const float* bn1b  = (const float*)d_in[7];
    const float* bn1m  = (const float*)d_in[8];
    const float* bn1v  = (const float*)d_in[9];
    const float* dsw   = (const float*)d_in[10];
    const float* dsb   = (const float*)d_in[11];
    const float* bn2g  = (const float*)d_in[12];
    const float* bn2b  = (const float*)d_in[13];
    const float* bn2m  = (const float*)d_in[14];
    const float* bn2v  = (const float*)d_in[15];

    // workspace layout (bytes). Total needed: 156,619,776 (~149.4 MiB)
    char* ws = (char*)d_ws;
    float*    pooled = (float*)(ws + 0);           //  2048 f32
    float*    kgen   = (float*)(ws + 8192);        // 18432 f32
    float*    a1     = (float*)(ws + 81920);       //  128 f32
    float*    b1     = (float*)(ws + 82432);
    float*    a2     = (float*)(ws + 82944);       //  512 f32
    float*    b2     = (float*)(ws + 84992);
    ushort_t* gpwbf  = (ushort_t*)(ws + 87040);    // 16384 bf16
    ushort_t* wds    = (ushort_t*)(ws + 119808);   // 512*2304 bf16
    ushort_t* comb   = (ushort_t*)(ws + 2479104);  // 16*112*2*56*256 bf16
    ushort_t* tbuf   = (ushort_t*)(ws + 105239552);// 200704*128 bf16
    // xT (NHWC bf16 copy of x) lives in d_out: exactly 102,760,448 B, consumed
    // by k_dwc before k_ds overwrites d_out with the real output.
    ushort_t* xT  = (ushort_t*)d_out;
    float*    out = (float*)d_out;

    k_prep<<<64, 256, 0, stream>>>(gpw_w, gpw_b, bn1g, bn1b, bn1m, bn1v,
                                   dsb, bn2g, bn2b, bn2m, bn2v,
                                   gpwbf, a1, b1, a2, b2);
    k_wds <<<4608, 256, 0, stream>>>(dsw, wds);
    k_pool<<<2048, 256, 0, stream>>>(x, pooled);
    k_kgen<<<72, 256, 0, stream>>>(pooled, wkg, kgen);
    k_xt  <<<1792, 256, 0, stream>>>(x, xT);
    k_dwc <<<100352, 256, 0, stream>>>(xT, kgen, gdw_w, gdw_b, comb, tbuf);
    k_pw  <<<3136, 256, 0, stream>>>(tbuf, gpwbf, a1, b1, comb);
    k_ds  <<<dim3(4, 896), 256, 0, stream>>>(comb, wds, a2, b2, out);
}

// Round 2
// 845.369 us; speedup vs baseline: 1.2204x; 1.2204x over previous
//
#include <hip/hip_runtime.h>

// ---------------------------------------------------------------------------
// LocalGlobalBlock on MI355X.
// Stages:
//   k_prep : fold BN1/BN2 + biases into per-channel (alpha,beta); gpw -> bf16
//   k_wds  : ds_w [512][256][3][3] fp32 -> wds bf16 [oc][khw*256+ic] (k-reordered)
//   k_pool : mean over HxW of local half -> pooled[16][128]
//   k_kgen : relu(pooled @ W_kg^T) -> kgen[16][128][9]
//   k_xt   : x NCHW fp32 -> xT NHWC bf16 (stored in d_out as scratch; exact fit)
//   k_dwc  : fused local per-sample dw-conv (-> comb ch 0..127) and global
//            dilated dw-conv (-> tbuf); 8ch/thread int4 loads, LDS-staged
//            weight table (R2 rewrite: was 2B-scalar-load bound, 337us)
//   k_pw   : 1x1 conv as MFMA GEMM + BN1 + ReLU -> comb ch 128..255
//   k_ds   : downsample 3x3 stride2 as implicit MFMA GEMM + BN2 + ReLU -> d_out
//
// comb layout: [b][h][parity][w2][ch] bf16, w = 2*w2+parity. For fixed (kh,kw)
// the stride-2 column gather becomes a contiguous w2 range (channel-minor), so
// the k_ds B-tile staging is 16B vector loads.
// ---------------------------------------------------------------------------

#define DEVI static __device__ __forceinline__

using bf16x8 = __attribute__((ext_vector_type(8))) short;  // 8 bf16 (4 VGPRs)
using f32x4  = __attribute__((ext_vector_type(4))) float;  // MFMA accumulator
typedef unsigned short ushort_t;

constexpr int Bn = 16, MID = 128, CHN = 256, Hh = 112, Wn = 112;
constexpr int OHn = 56, OWn = 56, OCn = 512;
constexpr int HW  = Hh * Wn;        // 12544
constexpr int NPX = Bn * HW;        // 200704
constexpr int KDS = CHN * 9;        // 2304
constexpr float EPSf = 1e-5f;

DEVI ushort_t f2b(float f) {  // fp32 -> bf16 RNE (finite data only)
    unsigned u = __float_as_uint(f);
    return (ushort_t)((u + 0x7FFFu + ((u >> 16) & 1u)) >> 16);
}
DEVI float b2f(ushort_t s) { return __uint_as_float(((unsigned)s) << 16); }

// ------------------------- k_prep ------------------------------------------
__global__ __launch_bounds__(256) void k_prep(
        const float* __restrict__ gpw_w, const float* __restrict__ gpw_b,
        const float* __restrict__ bn1g, const float* __restrict__ bn1b,
        const float* __restrict__ bn1m, const float* __restrict__ bn1v,
        const float* __restrict__ dsb,
        const float* __restrict__ bn2g, const float* __restrict__ bn2b,
        const float* __restrict__ bn2m, const float* __restrict__ bn2v,
        ushort_t* __restrict__ gpwbf,
        float* __restrict__ a1, float* __restrict__ b1,
        float* __restrict__ a2, float* __restrict__ b2) {
    int i = blockIdx.x * 256 + threadIdx.x;
    if (i < MID * MID) gpwbf[i] = f2b(gpw_w[i]);
    if (i < OCn) {
        float inv = bn2g[i] / sqrtf(bn2v[i] + EPSf);
        a2[i] = inv;
        b2[i] = bn2b[i] + (dsb[i] - bn2m[i]) * inv;   // folds ds bias + BN2
    }
    if (i < MID) {
        float inv = bn1g[i] / sqrtf(bn1v[i] + EPSf);
        a1[i] = inv;
        b1[i] = bn1b[i] + (gpw_b[i] - bn1m[i]) * inv; // folds 1x1 bias + BN1
    }
}

// ------------------------- k_wds -------------------------------------------
// wds[oc][khw*256 + ic] = bf16(ds_w[oc][ic][kh][kw]),  khw = kh*3+kw
__global__ __launch_bounds__(256) void k_wds(const float* __restrict__ dsw,
                                             ushort_t* __restrict__ wds) {
    int idx = blockIdx.x * 256 + threadIdx.x;          // < 512*2304
    int o = idx / KDS, k = idx % KDS;
    int khw = k / CHN, ic = k % CHN;
    wds[idx] = f2b(dsw[(size_t)(o * CHN + ic) * 9 + khw]);
}

// ------------------------- k_pool ------------------------------------------
__global__ __launch_bounds__(256) void k_pool(const float* __restrict__ x,
                                              float* __restrict__ pooled) {
    __shared__ float red[256];
    int bc = blockIdx.x;                 // b*128 + c (local half only)
    int b = bc >> 7, c = bc & 127;
    const float* p = x + (size_t)(b * CHN + c) * HW;
    float s = 0.f;
    for (int i = threadIdx.x; i < HW; i += 256) s += p[i];
    red[threadIdx.x] = s;
    __syncthreads();
    for (int st = 128; st > 0; st >>= 1) {
        if ((int)threadIdx.x < st) red[threadIdx.x] += red[threadIdx.x + st];
        __syncthreads();
    }
    if (threadIdx.x == 0) pooled[bc] = red[0] * (1.f / HW);
}

// ------------------------- k_kgen ------------------------------------------
__global__ __launch_bounds__(256) void k_kgen(const float* __restrict__ pooled,
                                              const float* __restrict__ wkg,
                                              float* __restrict__ kgen) {
    int idx = blockIdx.x * 256 + threadIdx.x;          // < 16*1152
    int b = idx / 1152, j = idx % 1152;
    const float* pr = pooled + b * MID;
    const float* wr = wkg + (size_t)j * MID;
    float s = 0.f;
#pragma unroll 8
    for (int i = 0; i < MID; i++) s += pr[i] * wr[i];
    kgen[idx] = fmaxf(s, 0.f);
}

// ------------------------- k_xt --------------------------------------------
// x[b][ch][h][w] fp32 -> xT[b][h][w][ch] bf16, one block per (b,h) row.
__global__ __launch_bounds__(256) void k_xt(const float* __restrict__ x,
                                            ushort_t* __restrict__ xT) {
    __shared__ ushort_t tile[Wn * 264];  // [w][ch], pad 264 breaks conflicts
    int bh = blockIdx.x;
    int b = bh / Hh, h = bh % Hh;
    const float* xp = x + ((size_t)b * CHN * Hh + h) * Wn; // + ch*HW + w
    for (int idx = threadIdx.x; idx < Wn * CHN; idx += 256) {
        int ch = idx / Wn, w = idx % Wn;               // lanes -> w (coalesced)
        tile[w * 264 + ch] = f2b(xp[(size_t)ch * HW + w]);
    }
    __syncthreads();
    int4* dst = (int4*)(xT + (size_t)bh * Wn * CHN);   // contiguous slab
    for (int q = threadIdx.x; q < Wn * CHN / 8; q += 256) {
        int w = q >> 5, c0 = (q & 31) << 3;
        dst[q] = *(const int4*)(tile + w * 264 + c0);
    }
}

// ------------------------- k_dwc -------------------------------------------
// R2 rewrite. Block = (h, b*2+branch). 256 threads = 16 w-lanes x 16 cgrps
// of 8 channels. Weight table (1152 f32: kgen[b] row or gdw_w) staged via LDS
// once per block; tap loads are int4 (8 bf16 ch, 16B/lane); each thread emits
// 7 w-positions x 8 channels. Wave-VMEM ~10x lower than the scalar version.
__global__ __launch_bounds__(256) void k_dwc(
        const ushort_t* __restrict__ xT, const float* __restrict__ kgen,
        const float* __restrict__ gdw_w, const float* __restrict__ gdw_b,
        ushort_t* __restrict__ comb, ushort_t* __restrict__ tbuf) {
    __shared__ float wtab[1152];         // [c][tap] fp32
    int t = threadIdx.x;
    int h  = blockIdx.x;                 // 0..111
    int by = blockIdx.y;                 // b*2 + br
    int b = by >> 1, br = by & 1;
    const float* wg = br ? gdw_w : (kgen + b * 1152);
    {
        const float4* src = (const float4*)wg;
        float4* dst = (float4*)wtab;
        dst[t] = src[t];
        if (t < 32) dst[256 + t] = src[256 + t];       // 288 float4 total
    }
    __syncthreads();
    int cg = t & 15, wlane = t >> 4;
    int c0 = cg << 3;
    float wk[9][8];
#pragma unroll
    for (int tp = 0; tp < 9; tp++)
#pragma unroll
        for (int k = 0; k < 8; k++)
            wk[tp][k] = wtab[(c0 + k) * 9 + tp];
    float bias[8] = {0.f, 0.f, 0.f, 0.f, 0.f, 0.f, 0.f, 0.f};
    if (br) {
        *(float4*)&bias[0] = *(const float4*)(gdw_b + c0);
        *(float4*)&bias[4] = *(const float4*)(gdw_b + c0 + 4);
    }
    const ushort_t* xb = xT + (size_t)b * HW * CHN + (br ? MID : 0) + c0;
    int dil = 1 + br;                    // local: dil 1 pad 1; global: dil 2 pad 2
    for (int ws = 0; ws < 7; ws++) {
        int w = ws * 16 + wlane;
        float acc[8];
#pragma unroll
        for (int k = 0; k < 8; k++) acc[k] = bias[k];
#pragma unroll
        for (int dh = -1; dh <= 1; dh++) {
            int h1 = h + dh * dil;       // wave-uniform bounds check
            if ((unsigned)h1 >= (unsigned)Hh) continue;
#pragma unroll
            for (int dw = -1; dw <= 1; dw++) {
                int w1 = w + dw * dil;
                if ((unsigned)w1 >= (unsigned)Wn) continue;
                union { int4 v; ushort_t u[8]; } U;
                U.v = *(const int4*)(xb + (size_t)(h1 * Wn + w1) * CHN);
                int tp = (dh + 1) * 3 + (dw + 1);
#pragma unroll
                for (int k = 0; k < 8; k++)
                    acc[k] += wk[tp][k] * b2f(U.u[k]);
            }
        }
        union { int4 v; ushort_t u[8]; } O;
#pragma unroll
        for (int k = 0; k < 8; k++) O.u[k] = f2b(acc[k]);
        if (br == 0)
            *(int4*)(comb + (((size_t)(b * Hh + h) * 2 + (w & 1)) * 56 + (w >> 1)) * CHN + c0) = O.v;
        else
            *(int4*)(tbuf + (size_t)(b * HW + h * Wn + w) * MID + c0) = O.v;
    }
}

// ------------------------- k_pw --------------------------------------------
// 1x1 conv: D[px][oc2] = sum_ci t[px][ci] * gpw[oc2][ci]; + BN1 + ReLU.
// MFMA 16x16x32 bf16, operands straight from global (both K-minor).
__global__ __launch_bounds__(256) void k_pw(
        const ushort_t* __restrict__ tbuf, const ushort_t* __restrict__ gpwbf,
        const float* __restrict__ a1, const float* __restrict__ b1,
        ushort_t* __restrict__ comb) {
    int t = threadIdx.x, lane = t & 63, wave = t >> 6;
    int px0 = blockIdx.x * 64 + wave * 16;
    int mrow = lane & 15, quad = lane >> 4;
    const short* tb = (const short*)tbuf;
    const short* gw = (const short*)gpwbf;
    f32x4 acc[8] = {};
#pragma unroll
    for (int kc = 0; kc < 4; kc++) {
        bf16x8 a = *(const bf16x8*)(tb + (size_t)(px0 + mrow) * MID + kc * 32 + quad * 8);
#pragma unroll
        for (int n = 0; n < 8; n++) {
            bf16x8 bf = *(const bf16x8*)(gw + (size_t)(n * 16 + mrow) * MID + kc * 32 + quad * 8);
            acc[n] = __builtin_amdgcn_mfma_f32_16x16x32_bf16(a, bf, acc[n], 0, 0, 0);
        }
    }
#pragma unroll
    for (int n = 0; n < 8; n++) {
        int oc2 = n * 16 + mrow;                        // D col = lane&15
        float al = a1[oc2], be = b1[oc2];
#pragma unroll
        for (int r = 0; r < 4; r++) {                   // D row = quad*4+reg
            int px = px0 + quad * 4 + r;
            float v = fmaxf(acc[n][r] * al + be, 0.f);
            int b = px / HW, rem = px % HW, h = rem / Wn, w = rem % Wn;
            comb[(((size_t)(b * Hh + h) * 2 + (w & 1)) * 56 + (w >> 1)) * CHN + MID + oc2] = f2b(v);
        }
    }
}

// ------------------------- k_ds --------------------------------------------
// Downsample 3x3 stride2 pad1 as implicit GEMM.
// Block tile: 128 oc x 64 ow (one (b,oh) output row, ow>=56 masked).
// K = 9*256, BK = 32 (fixed (kh,kw), 32 input channels per step).
__global__ __launch_bounds__(256) void k_ds(
        const ushort_t* __restrict__ comb, const ushort_t* __restrict__ wds,
        const float* __restrict__ a2, const float* __restrict__ b2,
        float* __restrict__ out) {
    __shared__ ushort_t lA[128 * 40];   // [oc][32k], stride 40 spreads banks
    __shared__ ushort_t lB[64 * 40];    // [ow][32k]
    int t = threadIdx.x, lane = t & 63, wave = t >> 6;
    int oc0 = blockIdx.x * 128;         // M-tile (x-fastest: share B in L2)
    int nt = blockIdx.y;                // (b, oh)
    int bb = nt / OHn, oh = nt % OHn;
    int mrow = lane & 15, quad = lane >> 4;
    const short* cb = (const short*)comb;
    const short* wd = (const short*)wds;
    int arow = t >> 2, akg = (t & 3) * 8;   // A staging: rows arow, arow+64
    int bow  = t >> 2, bkg = (t & 3) * 8;   // B staging: one ow per 4 lanes

    f32x4 acc[2][4] = {};
    for (int kt = 0; kt < 72; kt++) {
        int khw = kt >> 3, icc = kt & 7;
        int kh = khw / 3, kw = khw % 3;
        // --- gather next tiles into registers ---
        const short* wsrc = wd + (size_t)(oc0 + arow) * KDS + khw * 256 + icc * 32 + akg;
        int4 av0 = *(const int4*)wsrc;
        int4 av1 = *(const int4*)(wsrc + (size_t)64 * KDS);
        int r = 2 * oh - 1 + kh;                 // input row; -1 => zero pad
        int off = (kw == 0) ? -1 : 0;
        int p   = (kw == 1) ? 0 : 1;             // input col = 2*w2 + p
        int w2 = bow + off;
        int4 bv = {0, 0, 0, 0};
        if (r >= 0 && w2 >= 0 && w2 < 56)
            bv = *(const int4*)(cb + (((size_t)(bb * Hh + r) * 2 + p) * 56 + w2) * CHN
                                  + icc * 32 + bkg);
        // --- stage ---
        __syncthreads();
        *(int4*)(lA + arow * 40 + akg) = av0;
        *(int4*)(lA + (arow + 64) * 40 + akg) = av1;
        *(int4*)(lB + bow * 40 + bkg) = bv;
        __syncthreads();
        // --- MFMA: each wave 32oc x 64ow ---
        bf16x8 afr[2], bfr[4];
#pragma unroll
        for (int s = 0; s < 2; s++)
            afr[s] = *(const bf16x8*)(lA + (wave * 32 + s * 16 + mrow) * 40 + quad * 8);
#pragma unroll
        for (int n = 0; n < 4; n++)
            bfr[n] = *(const bf16x8*)(lB + (n * 16 + mrow) * 40 + quad * 8);
#pragma unroll
        for (int s = 0; s < 2; s++)
#pragma unroll
            for (int n = 0; n < 4; n++)
                acc[s][n] = __builtin_amdgcn_mfma_f32_16x16x32_bf16(afr[s], bfr[n], acc[s][n], 0, 0, 0);
    }
    // --- epilogue: BN2 + ReLU, mask padded ow ---
#pragma unroll
    for (int s = 0; s < 2; s++) {
#pragma unroll
        for (int r4 = 0; r4 < 4; r4++) {
            int oc = oc0 + wave * 32 + s * 16 + quad * 4 + r4;
            float al = a2[oc], be = b2[oc];
#pragma unroll
            for (int n = 0; n < 4; n++) {
                int ow = n * 16 + mrow;
                if (ow < OWn) {
                    float v = fmaxf(acc[s][n][r4] * al + be, 0.f);
                    out[(((size_t)(bb * OCn + oc) * OHn + oh)) * OWn + ow] = v;
                }
            }
        }
    }
}

// ------------------------- launch ------------------------------------------
extern "C" void kernel_launch(void* const* d_in, const int* in_sizes, int n_in,
                              void* d_out, int out_size, void* d_ws, size_t ws_size,
                              hipStream_t stream) {
    const float* x     = (const float*)d_in[0];
    const float* wkg   = (const float*)d_in[1];
    const float* gdw_w = (const float*)d_in[2];
    const float* gdw_b = (const float*)d_in[3];
    const float* gpw_w = (const float*)d_in[4];
    const float* gpw_b = (const float*)d_in[5];
    const float* bn1g  = (const float*)d_in[6];
    const float* bn1b  = (const float*)d_in[7];
    const float* bn1m  = (const float*)d_in[8];
    const float* bn1v  = (const float*)d_in[9];
    const float* dsw   = (const float*)d_in[10];
    const float* dsb   = (const float*)d_in[11];
    const float* bn2g  = (const float*)d_in[12];
    const float* bn2b  = (const float*)d_in[13];
    const float* bn2m  = (const float*)d_in[14];
    const float* bn2v  = (const float*)d_in[15];

    // workspace layout (bytes). Total needed: 156,619,776 (~149.4 MiB)
    char* ws = (char*)d_ws;
    float*    pooled = (float*)(ws + 0);           //  2048 f32
    float*    kgen   = (float*)(ws + 8192);        // 18432 f32
    float*    a1     = (float*)(ws + 81920);       //  128 f32
    float*    b1     = (float*)(ws + 82432);
    float*    a2     = (float*)(ws + 82944);       //  512 f32
    float*    b2     = (float*)(ws + 84992);
    ushort_t* gpwbf  = (ushort_t*)(ws + 87040);    // 16384 bf16
    ushort_t* wds    = (ushort_t*)(ws + 119808);   // 512*2304 bf16
    ushort_t* comb   = (ushort_t*)(ws + 2479104);  // 16*112*2*56*256 bf16
    ushort_t* tbuf   = (ushort_t*)(ws + 105239552);// 200704*128 bf16
    // xT (NHWC bf16 copy of x) lives in d_out: exactly 102,760,448 B, consumed
    // by k_dwc before k_ds overwrites d_out with the real output.
    ushort_t* xT  = (ushort_t*)d_out;
    float*    out = (float*)d_out;

    k_prep<<<64, 256, 0, stream>>>(gpw_w, gpw_b, bn1g, bn1b, bn1m, bn1v,
                                   dsb, bn2g, bn2b, bn2m, bn2v,
                                   gpwbf, a1, b1, a2, b2);
    k_wds <<<4608, 256, 0, stream>>>(dsw, wds);
    k_pool<<<2048, 256, 0, stream>>>(x, pooled);
    k_kgen<<<72, 256, 0, stream>>>(pooled, wkg, kgen);
    k_xt  <<<1792, 256, 0, stream>>>(x, xT);
    k_dwc <<<dim3(Hh, Bn * 2), 256, 0, stream>>>(xT, kgen, gdw_w, gdw_b, comb, tbuf);
    k_pw  <<<3136, 256, 0, stream>>>(tbuf, gpwbf, a1, b1, comb);
    k_ds  <<<dim3(4, 896), 256, 0, stream>>>(comb, wds, a2, b2, out);
}

// Round 3
// 741.455 us; speedup vs baseline: 1.3914x; 1.1401x over previous
//
#include <hip/hip_runtime.h>

// ---------------------------------------------------------------------------
// LocalGlobalBlock on MI355X.
//   k_prep : fold BN1/BN2 + biases into (alpha,beta); gpw -> bf16
//   k_wds  : ds_w -> wds2 bf16 [khw*4+icc][oc][64ch], 16B chunks XOR-swizzled
//            by (oc&7) so global_load_lds deposits a conflict-free LDS image
//   k_pool : mean over HxW of local half -> pooled[16][128]
//   k_kgen : relu(pooled @ W_kg^T) -> kgen[16][128][9]
//   k_xt   : x NCHW fp32 -> xT NHWC bf16 (in d_out as scratch; exact fit)
//   k_dwc  : fused local + global depthwise -> comb2 ch 0..127 / tbuf
//   k_pw   : 1x1 conv MFMA GEMM + BN1 + ReLU -> comb2 ch 128..255
//   k_ds   : downsample 3x3 s2 implicit GEMM (R3 rewrite): 128oc x 128n tile
//            (2 oh rows), BK=64, 36 steps x 32 MFMA/wave, ALL staging via
//            global_load_lds(16B), XOR-swizzled LDS, XCD-aware block decode.
//
// comb2 layout: [b][h][p][icc4][w2 56][64ch], w = 2*w2+p; chunk c (16B=8ch)
// stored at position c^(w2&7). For fixed (kh,kw,icc) one input row's B-slab
// is 56*128B contiguous -> pure DMA staging. Zero-pad (w2=-1, r=-1) handled
// by wave-uniform LDS zero-fills in k_ds (no guard storage).
// ---------------------------------------------------------------------------

#define DEVI static __device__ __forceinline__

using bf16x8 = __attribute__((ext_vector_type(8))) short;  // 8 bf16 (4 VGPRs)
using f32x4  = __attribute__((ext_vector_type(4))) float;  // MFMA accumulator
typedef unsigned short ushort_t;

constexpr int Bn = 16, MID = 128, CHN = 256, Hh = 112, Wn = 112;
constexpr int OHn = 56, OWn = 56, OCn = 512;
constexpr int HW  = Hh * Wn;        // 12544
constexpr int KDS = CHN * 9;        // 2304
constexpr float EPSf = 1e-5f;

// comb2 strides in ushorts
constexpr size_t C_I = 56 * 64;          // 3584  (per icc)
constexpr size_t C_P = 4 * C_I;          // 14336 (per parity)
constexpr size_t C_H = 2 * C_P;          // 28672 (per h row)
constexpr size_t C_B = (size_t)Hh * C_H; // 3211264 (per batch)

DEVI ushort_t f2b(float f) {  // fp32 -> bf16 RNE (finite data only)
    unsigned u = __float_as_uint(f);
    return (ushort_t)((u + 0x7FFFu + ((u >> 16) & 1u)) >> 16);
}
DEVI float b2f(ushort_t s) { return __uint_as_float(((unsigned)s) << 16); }

DEVI void gl_lds16(const void* g, void* l) {   // async global->LDS, 16B/lane
    __builtin_amdgcn_global_load_lds(
        (const __attribute__((address_space(1))) unsigned int*)g,
        (__attribute__((address_space(3))) unsigned int*)l, 16, 0, 0);
}

// ------------------------- k_prep ------------------------------------------
__global__ __launch_bounds__(256) void k_prep(
        const float* __restrict__ gpw_w, const float* __restrict__ gpw_b,
        const float* __restrict__ bn1g, const float* __restrict__ bn1b,
        const float* __restrict__ bn1m, const float* __restrict__ bn1v,
        const float* __restrict__ dsb,
        const float* __restrict__ bn2g, const float* __restrict__ bn2b,
        const float* __restrict__ bn2m, const float* __restrict__ bn2v,
        ushort_t* __restrict__ gpwbf,
        float* __restrict__ a1, float* __restrict__ b1,
        float* __restrict__ a2, float* __restrict__ b2) {
    int i = blockIdx.x * 256 + threadIdx.x;
    if (i < MID * MID) gpwbf[i] = f2b(gpw_w[i]);
    if (i < OCn) {
        float inv = bn2g[i] / sqrtf(bn2v[i] + EPSf);
        a2[i] = inv;
        b2[i] = bn2b[i] + (dsb[i] - bn2m[i]) * inv;   // folds ds bias + BN2
    }
    if (i < MID) {
        float inv = bn1g[i] / sqrtf(bn1v[i] + EPSf);
        a1[i] = inv;
        b1[i] = bn1b[i] + (gpw_b[i] - bn1m[i]) * inv; // folds 1x1 bias + BN1
    }
}

// ------------------------- k_wds -------------------------------------------
// wds2[kb][oc][64], kb = khw*4+icc; chunk ph holds logical chunk ph^(oc&7).
__global__ __launch_bounds__(256) void k_wds(const float* __restrict__ dsw,
                                             ushort_t* __restrict__ wds2) {
    int d = blockIdx.x * 256 + threadIdx.x;        // < 36*512*64 = 1179648
    int j = d & 63, oc = (d >> 6) & 511, kb = d >> 15;
    int khw = kb >> 2, icc = kb & 3;
    int ph = j >> 3, c = ph ^ (oc & 7);
    int ic = icc * 64 + c * 8 + (j & 7);
    wds2[d] = f2b(dsw[((size_t)oc * CHN + ic) * 9 + khw]);
}

// ------------------------- k_pool ------------------------------------------
__global__ __launch_bounds__(256) void k_pool(const float* __restrict__ x,
                                              float* __restrict__ pooled) {
    __shared__ float red[256];
    int bc = blockIdx.x;                 // b*128 + c (local half only)
    int b = bc >> 7, c = bc & 127;
    const float* p = x + (size_t)(b * CHN + c) * HW;
    float s = 0.f;
    for (int i = threadIdx.x; i < HW; i += 256) s += p[i];
    red[threadIdx.x] = s;
    __syncthreads();
    for (int st = 128; st > 0; st >>= 1) {
        if ((int)threadIdx.x < st) red[threadIdx.x] += red[threadIdx.x + st];
        __syncthreads();
    }
    if (threadIdx.x == 0) pooled[bc] = red[0] * (1.f / HW);
}

// ------------------------- k_kgen ------------------------------------------
__global__ __launch_bounds__(256) void k_kgen(const float* __restrict__ pooled,
                                              const float* __restrict__ wkg,
                                              float* __restrict__ kgen) {
    int idx = blockIdx.x * 256 + threadIdx.x;          // < 16*1152
    int b = idx / 1152, j = idx % 1152;
    const float* pr = pooled + b * MID;
    const float* wr = wkg + (size_t)j * MID;
    float s = 0.f;
#pragma unroll 8
    for (int i = 0; i < MID; i++) s += pr[i] * wr[i];
    kgen[idx] = fmaxf(s, 0.f);
}

// ------------------------- k_xt --------------------------------------------
// x[b][ch][h][w] fp32 -> xT[b][h][w][ch] bf16, one block per (b,h) row.
__global__ __launch_bounds__(256) void k_xt(const float* __restrict__ x,
                                            ushort_t* __restrict__ xT) {
    __shared__ ushort_t tile[Wn * 264];  // [w][ch], pad 264 breaks conflicts
    int bh = blockIdx.x;
    int b = bh / Hh, h = bh % Hh;
    const float* xp = x + ((size_t)b * CHN * Hh + h) * Wn; // + ch*HW + w
    for (int idx = threadIdx.x; idx < Wn * CHN; idx += 256) {
        int ch = idx / Wn, w = idx % Wn;               // lanes -> w (coalesced)
        tile[w * 264 + ch] = f2b(xp[(size_t)ch * HW + w]);
    }
    __syncthreads();
    int4* dst = (int4*)(xT + (size_t)bh * Wn * CHN);   // contiguous slab
    for (int q = threadIdx.x; q < Wn * CHN / 8; q += 256) {
        int w = q >> 5, c0 = (q & 31) << 3;
        dst[q] = *(const int4*)(tile + w * 264 + c0);
    }
}

// ------------------------- k_dwc -------------------------------------------
// Block = (h, b*2+branch). 256 threads = 16 w-lanes x 16 cgrps of 8 channels.
__global__ __launch_bounds__(256) void k_dwc(
        const ushort_t* __restrict__ xT, const float* __restrict__ kgen,
        const float* __restrict__ gdw_w, const float* __restrict__ gdw_b,
        ushort_t* __restrict__ comb, ushort_t* __restrict__ tbuf) {
    __shared__ float wtab[1152];         // [c][tap] fp32
    int t = threadIdx.x;
    int h  = blockIdx.x;                 // 0..111
    int by = blockIdx.y;                 // b*2 + br
    int b = by >> 1, br = by & 1;
    const float* wg = br ? gdw_w : (kgen + b * 1152);
    {
        const float4* src = (const float4*)wg;
        float4* dst = (float4*)wtab;
        dst[t] = src[t];
        if (t < 32) dst[256 + t] = src[256 + t];       // 288 float4 total
    }
    __syncthreads();
    int cg = t & 15, wlane = t >> 4;
    int c0 = cg << 3;
    float wk[9][8];
#pragma unroll
    for (int tp = 0; tp < 9; tp++)
#pragma unroll
        for (int k = 0; k < 8; k++)
            wk[tp][k] = wtab[(c0 + k) * 9 + tp];
    float bias[8] = {0.f, 0.f, 0.f, 0.f, 0.f, 0.f, 0.f, 0.f};
    if (br) {
        *(float4*)&bias[0] = *(const float4*)(gdw_b + c0);
        *(float4*)&bias[4] = *(const float4*)(gdw_b + c0 + 4);
    }
    const ushort_t* xb = xT + (size_t)b * HW * CHN + (br ? MID : 0) + c0;
    int dil = 1 + br;                    // local: dil 1 pad 1; global: dil 2 pad 2
    for (int ws = 0; ws < 7; ws++) {
        int w = ws * 16 + wlane;
        float acc[8];
#pragma unroll
        for (int k = 0; k < 8; k++) acc[k] = bias[k];
#pragma unroll
        for (int dh = -1; dh <= 1; dh++) {
            int h1 = h + dh * dil;       // wave-uniform bounds check
            if ((unsigned)h1 >= (unsigned)Hh) continue;
#pragma unroll
            for (int dw = -1; dw <= 1; dw++) {
                int w1 = w + dw * dil;
                if ((unsigned)w1 >= (unsigned)Wn) continue;
                union { int4 v; ushort_t u[8]; } U;
                U.v = *(const int4*)(xb + (size_t)(h1 * Wn + w1) * CHN);
                int tp = (dh + 1) * 3 + (dw + 1);
#pragma unroll
                for (int k = 0; k < 8; k++)
                    acc[k] += wk[tp][k] * b2f(U.u[k]);
            }
        }
        union { int4 v; ushort_t u[8]; } O;
#pragma unroll
        for (int k = 0; k < 8; k++) O.u[k] = f2b(acc[k]);
        if (br == 0) {
            int w2 = w >> 1, p = w & 1;
            int icc = c0 >> 6, cch = (c0 & 63) >> 3, ph = cch ^ (w2 & 7);
            *(int4*)(comb + (size_t)b * C_B + (size_t)h * C_H + p * C_P
                     + icc * C_I + w2 * 64 + ph * 8) = O.v;
        } else {
            *(int4*)(tbuf + (size_t)(b * HW + h * Wn + w) * MID + c0) = O.v;
        }
    }
}

// ------------------------- k_pw --------------------------------------------
// 1x1 conv: D[px][oc2] = sum_ci t[px][ci] * gpw[oc2][ci]; + BN1 + ReLU.
__global__ __launch_bounds__(256) void k_pw(
        const ushort_t* __restrict__ tbuf, const ushort_t* __restrict__ gpwbf,
        const float* __restrict__ a1, const float* __restrict__ b1,
        ushort_t* __restrict__ comb) {
    int t = threadIdx.x, lane = t & 63, wave = t >> 6;
    int px0 = blockIdx.x * 64 + wave * 16;
    int mrow = lane & 15, quad = lane >> 4;
    const short* tb = (const short*)tbuf;
    const short* gw = (const short*)gpwbf;
    f32x4 acc[8] = {};
#pragma unroll
    for (int kc = 0; kc < 4; kc++) {
        bf16x8 a = *(const bf16x8*)(tb + (size_t)(px0 + mrow) * MID + kc * 32 + quad * 8);
#pragma unroll
        for (int n = 0; n < 8; n++) {
            bf16x8 bf = *(const bf16x8*)(gw + (size_t)(n * 16 + mrow) * MID + kc * 32 + quad * 8);
            acc[n] = __builtin_amdgcn_mfma_f32_16x16x32_bf16(a, bf, acc[n], 0, 0, 0);
        }
    }
#pragma unroll
    for (int n = 0; n < 8; n++) {
        int oc2 = n * 16 + mrow;                        // D col = lane&15
        float al = a1[oc2], be = b1[oc2];
#pragma unroll
        for (int r = 0; r < 4; r++) {                   // D row = quad*4+reg
            int px = px0 + quad * 4 + r;
            float v = fmaxf(acc[n][r] * al + be, 0.f);
            int b = px / HW, rem = px % HW, h = rem / Wn, w = rem % Wn;
            int w2 = w >> 1, p = w & 1;
            int gch = MID + oc2;                        // 128..255
            int icc = gch >> 6, cch = (gch & 63) >> 3, ph = cch ^ (w2 & 7);
            comb[(size_t)b * C_B + (size_t)h * C_H + p * C_P + icc * C_I
                 + w2 * 64 + ph * 8 + (oc2 & 7)] = f2b(v);
        }
    }
}

// ------------------------- k_ds (R3) ---------------------------------------
// 128 oc x 128 n (2 oh rows x 56 ow + pad), BK=64, 36 steps x 32 MFMA/wave.
// All staging via global_load_lds(16B); swizzled LDS -> conflict-free reads.
__global__ __launch_bounds__(256) void k_ds(
        const ushort_t* __restrict__ comb, const ushort_t* __restrict__ wds2,
        const float* __restrict__ a2, const float* __restrict__ b2,
        float* __restrict__ out) {
    __shared__ ushort_t lA[128 * 64];   // [oc][64ch], 16 KB, chunk-swizzled
    __shared__ ushort_t lB[128 * 64];   // [n][64ch],  16 KB, chunk-swizzled
    int t = threadIdx.x, lane = t & 63, wave = t >> 6;
    // XCD-aware decode: 4 oc-tiles of one (b,oh-pair) -> same XCD, contiguous
    int g = blockIdx.x;
    int xcd = g & 7, s = g >> 3;        // s in [0,224)
    int octile = s & 3, pl = s >> 2;    // pl in [0,56)
    int pair = xcd * 56 + pl;           // [0,448)
    int bb = pair / 28, ohp = pair % 28;
    int oh0 = ohp * 2, oc0 = octile * 128;
    int mrow = lane & 15, quad = lane >> 4;
    int wm = wave & 1, wn = wave >> 1;
    int ak = mrow & 7;                  // A swizzle key (row&7 == mrow&7)

    f32x4 acc[4][4] = {};
    for (int kt = 0; kt < 36; kt++) {
        int khw = kt >> 2, icc = kt & 3;
        int kh = khw / 3, kw = khw - kh * 3;
        int p = (kw == 1) ? 0 : 1;
        bool zh0 = (oh0 == 0) && (kh == 0);        // r=-1: zero half 0
        int ldsShift = (kw == 0) ? 128 : 0;        // row0 holds w2=-1 zeros
        __syncthreads();
        if (zh0) {
            int4 z = {0, 0, 0, 0};
            *(int4*)(lB + t * 8) = z;
            *(int4*)(lB + 2048 + t * 8) = z;
        }
        if (kw == 0 && t < 16) {                   // zero w2=-1 row, both halves
            int4 z = {0, 0, 0, 0};
            *(int4*)(lB + (t >> 3) * 4096 + (t & 7) * 8) = z;
        }
        // --- A: 16 KB contiguous slab, 4 DMA per wave ---
        const char* asrc = (const char*)wds2
            + ((size_t)kt * 32768 + (size_t)oc0 * 64) * 2 + lane * 16;
#pragma unroll
        for (int i = 0; i < 4; i++) {
            int j = wave * 4 + i;
            gl_lds16(asrc + j * 1024, (char*)lA + j * 1024);
        }
        // --- B: two 7 KB row-slabs, 14 DMA round-robin over waves ---
        for (int j = wave; j < 14; j += 4) {
            int osub = (j >= 7) ? 1 : 0, jj = j - osub * 7;
            if (zh0 && osub == 0) continue;
            int r = 2 * oh0 + 2 * osub + kh - 1;   // 0..111 here
            const char* bsrc = (const char*)comb
                + ((size_t)bb * C_B + (size_t)r * C_H + (size_t)p * C_P
                   + (size_t)icc * C_I) * 2 + jj * 1024 + lane * 16;
            gl_lds16(bsrc, (char*)lB + osub * 8192 + ldsShift + jj * 1024);
        }
        __syncthreads();
        // --- frags + MFMA: wave (wm,wn) computes 64oc x 64n ---
        int bk = (mrow + ((kw == 0) ? 7 : 0)) & 7; // B swizzle key
#pragma unroll
        for (int ks = 0; ks < 2; ks++) {
            bf16x8 af[4], bf[4];
#pragma unroll
            for (int m = 0; m < 4; m++) {
                int row = wm * 64 + m * 16 + mrow;
                int ph = (ks * 4 + quad) ^ ak;
                af[m] = *(const bf16x8*)(lA + row * 64 + ph * 8);
            }
#pragma unroll
            for (int n = 0; n < 4; n++) {
                int nr = wn * 64 + n * 16 + mrow;
                int ph = (ks * 4 + quad) ^ bk;
                bf[n] = *(const bf16x8*)(lB + nr * 64 + ph * 8);
            }
#pragma unroll
            for (int m = 0; m < 4; m++)
#pragma unroll
                for (int n = 0; n < 4; n++)
                    acc[m][n] = __builtin_amdgcn_mfma_f32_16x16x32_bf16(
                        af[m], bf[n], acc[m][n], 0, 0, 0);
        }
    }
    // --- epilogue: BN2 + ReLU; D row=oc (quad*4+r), col=n (mrow) ---
#pragma unroll
    for (int m = 0; m < 4; m++) {
#pragma unroll
        for (int r4 = 0; r4 < 4; r4++) {
            int oc = oc0 + wm * 64 + m * 16 + quad * 4 + r4;
            float al = a2[oc], be = b2[oc];
#pragma unroll
            for (int n = 0; n < 4; n++) {
                int nr = wn * 64 + n * 16 + mrow;
                int osub = nr >> 6, ow = nr & 63;
                if (ow < OWn) {
                    float v = fmaxf(acc[m][n][r4] * al + be, 0.f);
                    out[((size_t)(bb * OCn + oc) * OHn + (oh0 + osub)) * OWn + ow] = v;
                }
            }
        }
    }
}

// ------------------------- launch ------------------------------------------
extern "C" void kernel_launch(void* const* d_in, const int* in_sizes, int n_in,
                              void* d_out, int out_size, void* d_ws, size_t ws_size,
                              hipStream_t stream) {
    const float* x     = (const float*)d_in[0];
    const float* wkg   = (const float*)d_in[1];
    const float* gdw_w = (const float*)d_in[2];
    const float* gdw_b = (const float*)d_in[3];
    const float* gpw_w = (const float*)d_in[4];
    const float* gpw_b = (const float*)d_in[5];
    const float* bn1g  = (const float*)d_in[6];
    const float* bn1b  = (const float*)d_in[7];
    const float* bn1m  = (const float*)d_in[8];
    const float* bn1v  = (const float*)d_in[9];
    const float* dsw   = (const float*)d_in[10];
    const float* dsb   = (const float*)d_in[11];
    const float* bn2g  = (const float*)d_in[12];
    const float* bn2b  = (const float*)d_in[13];
    const float* bn2m  = (const float*)d_in[14];
    const float* bn2v  = (const float*)d_in[15];

    // workspace layout (bytes). Total: 156,619,776 (same proven footprint)
    char* ws = (char*)d_ws;
    float*    pooled = (float*)(ws + 0);           //  2048 f32
    float*    kgen   = (float*)(ws + 8192);        // 18432 f32
    float*    a1     = (float*)(ws + 81920);       //  128 f32
    float*    b1     = (float*)(ws + 82432);
    float*    a2     = (float*)(ws + 82944);       //  512 f32
    float*    b2     = (float*)(ws + 84992);
    ushort_t* gpwbf  = (ushort_t*)(ws + 87040);    // 16384 bf16
    ushort_t* wds2   = (ushort_t*)(ws + 119808);   // 36*512*64 bf16 (2.36 MB)
    ushort_t* comb   = (ushort_t*)(ws + 2479104);  // 102,760,448 B
    ushort_t* tbuf   = (ushort_t*)(ws + 105239552);// 200704*128 bf16
    // xT (NHWC bf16 copy of x) lives in d_out: exactly 102,760,448 B, consumed
    // by k_dwc before k_ds overwrites d_out with the real output.
    ushort_t* xT  = (ushort_t*)d_out;
    float*    out = (float*)d_out;

    k_prep<<<64, 256, 0, stream>>>(gpw_w, gpw_b, bn1g, bn1b, bn1m, bn1v,
                                   dsb, bn2g, bn2b, bn2m, bn2v,
                                   gpwbf, a1, b1, a2, b2);
    k_wds <<<4608, 256, 0, stream>>>(dsw, wds2);
    k_pool<<<2048, 256, 0, stream>>>(x, pooled);
    k_kgen<<<72, 256, 0, stream>>>(pooled, wkg, kgen);
    k_xt  <<<1792, 256, 0, stream>>>(x, xT);
    k_dwc <<<dim3(Hh, Bn * 2), 256, 0, stream>>>(xT, kgen, gdw_w, gdw_b, comb, tbuf);
    k_pw  <<<3136, 256, 0, stream>>>(tbuf, gpwbf, a1, b1, comb);
    k_ds  <<<1792, 256, 0, stream>>>(comb, wds2, a2, b2, out);
}

// Round 4
// 676.634 us; speedup vs baseline: 1.5247x; 1.0958x over previous
//
#include <hip/hip_runtime.h>

// ---------------------------------------------------------------------------
// LocalGlobalBlock on MI355X.  (R4: pipeline collapsed to 5 kernels)
//   k_prep : fold BN1/BN2 + biases into (alpha,beta); gpw -> bf16; zero pooled
//   k_wds  : ds_w -> wds2 bf16 [khw*4+icc][oc][64ch], 16B chunks XOR-swizzled
//   k_xt   : x NCHW fp32 -> xT NHWC bf16 (in d_out; exact fit) + fused pool
//            (per-row LDS reduce + atomicAdd into pooled sums)
//   k_kgen : relu((pooled_sum/HW) @ W_kg^T) -> kgen[16][128][9]
//   k_dwc  : br=0: local per-sample dw-conv -> comb ch 0..127
//            br=1: global dilated dw-conv -> LDS P -> in-block 1x1 MFMA GEMM
//                  + BN1 + ReLU -> comb ch 128..255  (k_pw fused, tbuf gone)
//   k_ds   : downsample 3x3 s2 implicit GEMM, 128oc x 128n, BK=64,
//            global_load_lds(16B) staging, XOR-swizzled LDS, XCD-aware decode
//
// comb layout: [b][h][p][icc4][w2 56][64ch], w = 2*w2+p; chunk c (16B=8ch)
// stored at position c^(w2&7) -> k_ds DMA deposits a conflict-free LDS image.
// ---------------------------------------------------------------------------

#define DEVI static __device__ __forceinline__

using bf16x8 = __attribute__((ext_vector_type(8))) short;  // 8 bf16 (4 VGPRs)
using f32x4  = __attribute__((ext_vector_type(4))) float;  // MFMA accumulator
typedef unsigned short ushort_t;

constexpr int Bn = 16, MID = 128, CHN = 256, Hh = 112, Wn = 112;
constexpr int OHn = 56, OWn = 56, OCn = 512;
constexpr int HW  = Hh * Wn;        // 12544
constexpr int KDS = CHN * 9;        // 2304
constexpr float EPSf = 1e-5f;

// comb strides in ushorts
constexpr size_t C_I = 56 * 64;          // 3584  (per icc)
constexpr size_t C_P = 4 * C_I;          // 14336 (per parity)
constexpr size_t C_H = 2 * C_P;          // 28672 (per h row)
constexpr size_t C_B = (size_t)Hh * C_H; // 3211264 (per batch)

DEVI ushort_t f2b(float f) {  // fp32 -> bf16 RNE (finite data only)
    unsigned u = __float_as_uint(f);
    return (ushort_t)((u + 0x7FFFu + ((u >> 16) & 1u)) >> 16);
}
DEVI float b2f(ushort_t s) { return __uint_as_float(((unsigned)s) << 16); }

DEVI void gl_lds16(const void* g, void* l) {   // async global->LDS, 16B/lane
    __builtin_amdgcn_global_load_lds(
        (const __attribute__((address_space(1))) unsigned int*)g,
        (__attribute__((address_space(3))) unsigned int*)l, 16, 0, 0);
}

// ------------------------- k_prep ------------------------------------------
__global__ __launch_bounds__(256) void k_prep(
        const float* __restrict__ gpw_w, const float* __restrict__ gpw_b,
        const float* __restrict__ bn1g, const float* __restrict__ bn1b,
        const float* __restrict__ bn1m, const float* __restrict__ bn1v,
        const float* __restrict__ dsb,
        const float* __restrict__ bn2g, const float* __restrict__ bn2b,
        const float* __restrict__ bn2m, const float* __restrict__ bn2v,
        ushort_t* __restrict__ gpwbf,
        float* __restrict__ a1, float* __restrict__ b1,
        float* __restrict__ a2, float* __restrict__ b2,
        float* __restrict__ pooled) {
    int i = blockIdx.x * 256 + threadIdx.x;
    if (i < MID * MID) gpwbf[i] = f2b(gpw_w[i]);
    if (i < Bn * MID) pooled[i] = 0.f;                // atomic accumulator init
    if (i < OCn) {
        float inv = bn2g[i] / sqrtf(bn2v[i] + EPSf);
        a2[i] = inv;
        b2[i] = bn2b[i] + (dsb[i] - bn2m[i]) * inv;   // folds ds bias + BN2
    }
    if (i < MID) {
        float inv = bn1g[i] / sqrtf(bn1v[i] + EPSf);
        a1[i] = inv;
        b1[i] = bn1b[i] + (gpw_b[i] - bn1m[i]) * inv; // folds 1x1 bias + BN1
    }
}

// ------------------------- k_wds -------------------------------------------
// wds2[kb][oc][64], kb = khw*4+icc; chunk ph holds logical chunk ph^(oc&7).
__global__ __launch_bounds__(256) void k_wds(const float* __restrict__ dsw,
                                             ushort_t* __restrict__ wds2) {
    int d = blockIdx.x * 256 + threadIdx.x;        // < 36*512*64 = 1179648
    int j = d & 63, oc = (d >> 6) & 511, kb = d >> 15;
    int khw = kb >> 2, icc = kb & 3;
    int ph = j >> 3, c = ph ^ (oc & 7);
    int ic = icc * 64 + c * 8 + (j & 7);
    wds2[d] = f2b(dsw[((size_t)oc * CHN + ic) * 9 + khw]);
}

// ------------------------- k_kgen ------------------------------------------
__global__ __launch_bounds__(256) void k_kgen(const float* __restrict__ pooled,
                                              const float* __restrict__ wkg,
                                              float* __restrict__ kgen) {
    int idx = blockIdx.x * 256 + threadIdx.x;          // < 16*1152
    int b = idx / 1152, j = idx % 1152;
    const float* pr = pooled + b * MID;                // channel SUMS (not mean)
    const float* wr = wkg + (size_t)j * MID;
    float s = 0.f;
#pragma unroll 8
    for (int i = 0; i < MID; i++) s += pr[i] * wr[i];
    kgen[idx] = fmaxf(s * (1.f / HW), 0.f);
}

// ------------------------- k_xt --------------------------------------------
// x[b][ch][h][w] fp32 -> xT[b][h][w][ch] bf16, one block per (b,h) row.
// Fused: channel sums of the local half -> atomicAdd pooled[b][c].
__global__ __launch_bounds__(256) void k_xt(const float* __restrict__ x,
                                            ushort_t* __restrict__ xT,
                                            float* __restrict__ pooled) {
    __shared__ ushort_t tile[Wn * 264];  // [w][ch], pad 264 breaks conflicts
    int t = threadIdx.x;
    int bh = blockIdx.x;
    int b = bh / Hh, h = bh % Hh;
    const float* xp = x + ((size_t)b * CHN * Hh + h) * Wn; // + ch*HW + w
    for (int idx = t; idx < CHN * 28; idx += 256) {    // float4 over w
        int ch = idx / 28, q = idx % 28;
        float4 v = *(const float4*)(xp + (size_t)ch * HW + q * 4);
        int w = q * 4;
        tile[w * 264 + ch]       = f2b(v.x);
        tile[(w + 1) * 264 + ch] = f2b(v.y);
        tile[(w + 2) * 264 + ch] = f2b(v.z);
        tile[(w + 3) * 264 + ch] = f2b(v.w);
    }
    __syncthreads();
    int4* dst = (int4*)(xT + (size_t)bh * Wn * CHN);   // contiguous slab
    for (int q = t; q < Wn * CHN / 8; q += 256) {
        int w = q >> 5, c0 = (q & 31) << 3;
        dst[q] = *(const int4*)(tile + w * 264 + c0);
    }
    if (t < MID) {                                     // pool local half
        float s = 0.f;
        for (int w = 0; w < Wn; w++) s += b2f(tile[w * 264 + t]);
        atomicAdd(&pooled[b * MID + t], s);
    }
}

// ------------------------- k_dwc (+ fused 1x1) ------------------------------
// Block = (h, b*2+branch). 256 threads = 16 w-lanes x 16 cgrps of 8 channels.
// br=0: local dw -> comb ch 0..127.
// br=1: global dw -> LDS P[112][128] (chunk-swizzled) -> MFMA 1x1 (M=112 px,
//       N=128 oc2, K=128 ci; B-frags from L2-resident gpwbf) -> BN1+ReLU ->
//       LDS EP[112][136] -> 16B stores to comb ch 128..255.
__global__ __launch_bounds__(256) void k_dwc(
        const ushort_t* __restrict__ xT, const float* __restrict__ kgen,
        const float* __restrict__ gdw_w, const float* __restrict__ gdw_b,
        const ushort_t* __restrict__ gpwbf,
        const float* __restrict__ a1, const float* __restrict__ b1,
        ushort_t* __restrict__ comb) {
    __shared__ float wtab[1152];          // [c][tap] fp32
    __shared__ ushort_t pbuf[112 * 136];  // union: P (112*128) / EP (112*136)
    int t = threadIdx.x;
    int h  = blockIdx.x;                  // 0..111
    int by = blockIdx.y;                  // b*2 + br
    int b = by >> 1, br = by & 1;
    const float* wg = br ? gdw_w : (kgen + b * 1152);
    {
        const float4* src = (const float4*)wg;
        float4* dstw = (float4*)wtab;
        dstw[t] = src[t];
        if (t < 32) dstw[256 + t] = src[256 + t];      // 288 float4 total
    }
    __syncthreads();
    int cg = t & 15, wlane = t >> 4;
    int c0 = cg << 3;
    float wk[9][8];
#pragma unroll
    for (int tp = 0; tp < 9; tp++)
#pragma unroll
        for (int k = 0; k < 8; k++)
            wk[tp][k] = wtab[(c0 + k) * 9 + tp];
    float bias[8] = {0.f, 0.f, 0.f, 0.f, 0.f, 0.f, 0.f, 0.f};
    if (br) {
        *(float4*)&bias[0] = *(const float4*)(gdw_b + c0);
        *(float4*)&bias[4] = *(const float4*)(gdw_b + c0 + 4);
    }
    const ushort_t* xb = xT + (size_t)b * HW * CHN + (br ? MID : 0) + c0;
    int dil = 1 + br;                    // local: dil 1 pad 1; global: dil 2 pad 2
    for (int ws = 0; ws < 7; ws++) {
        int w = ws * 16 + wlane;
        float acc[8];
#pragma unroll
        for (int k = 0; k < 8; k++) acc[k] = bias[k];
#pragma unroll
        for (int dh = -1; dh <= 1; dh++) {
            int h1 = h + dh * dil;       // wave-uniform bounds check
            if ((unsigned)h1 >= (unsigned)Hh) continue;
#pragma unroll
            for (int dw = -1; dw <= 1; dw++) {
                int w1 = w + dw * dil;
                if ((unsigned)w1 >= (unsigned)Wn) continue;
                union { int4 v; ushort_t u[8]; } U;
                U.v = *(const int4*)(xb + (size_t)(h1 * Wn + w1) * CHN);
                int tp = (dh + 1) * 3 + (dw + 1);
#pragma unroll
                for (int k = 0; k < 8; k++)
                    acc[k] += wk[tp][k] * b2f(U.u[k]);
            }
        }
        union { int4 v; ushort_t u[8]; } O;
#pragma unroll
        for (int k = 0; k < 8; k++) O.u[k] = f2b(acc[k]);
        if (br == 0) {
            int w2 = w >> 1, p = w & 1;
            int icc = c0 >> 6, cch = (c0 & 63) >> 3, ph = cch ^ (w2 & 7);
            *(int4*)(comb + (size_t)b * C_B + (size_t)h * C_H + p * C_P
                     + icc * C_I + w2 * 64 + ph * 8) = O.v;
        } else {
            int ph = cg ^ wlane;                        // P chunk swizzle
            *(int4*)(pbuf + (size_t)w * 128 + ph * 8) = O.v;
        }
    }
    if (br == 0) return;
    __syncthreads();                     // P complete
    // --- in-block 1x1 MFMA: D[px][oc2] = P[px][:] . gpwbf[oc2][:] ---
    int lane = t & 63, wave = t >> 6;
    int mrow = lane & 15, quad = lane >> 4;
    const short* gw = (const short*)gpwbf;
    f32x4 acc2[7][2] = {};
#pragma unroll
    for (int ks = 0; ks < 4; ks++) {
        bf16x8 bfr[2];
#pragma unroll
        for (int n = 0; n < 2; n++)
            bfr[n] = *(const bf16x8*)(gw + (size_t)(wave * 32 + n * 16 + mrow) * MID
                                         + ks * 32 + quad * 8);
#pragma unroll
        for (int m = 0; m < 7; m++) {
            int ph = (ks * 4 + quad) ^ mrow;
            bf16x8 af = *(const bf16x8*)(pbuf + (size_t)(m * 16 + mrow) * 128 + ph * 8);
#pragma unroll
            for (int n = 0; n < 2; n++)
                acc2[m][n] = __builtin_amdgcn_mfma_f32_16x16x32_bf16(
                    af, bfr[n], acc2[m][n], 0, 0, 0);
        }
    }
    __syncthreads();                     // all waves done reading P -> EP overlay
#pragma unroll
    for (int m = 0; m < 7; m++)
#pragma unroll
        for (int n = 0; n < 2; n++) {
            int oc2 = wave * 32 + n * 16 + mrow;        // D col = lane&15
            float al = a1[oc2], be = b1[oc2];
#pragma unroll
            for (int r = 0; r < 4; r++) {               // D row = quad*4+reg
                int px = m * 16 + quad * 4 + r;
                pbuf[px * 136 + oc2] = f2b(fmaxf(acc2[m][n][r] * al + be, 0.f));
            }
        }
    __syncthreads();                     // EP complete
    for (int ws = 0; ws < 7; ws++) {     // 16B stores, comb-swizzled
        int w = ws * 16 + wlane;
        int4 v = *(const int4*)(pbuf + (size_t)w * 136 + c0);
        int w2 = w >> 1, p = w & 1;
        int gch = MID + c0;
        int icc = gch >> 6, cch = (gch & 63) >> 3, ph = cch ^ (w2 & 7);
        *(int4*)(comb + (size_t)b * C_B + (size_t)h * C_H + p * C_P
                 + icc * C_I + w2 * 64 + ph * 8) = v;
    }
}

// ------------------------- k_ds --------------------------------------------
// 128 oc x 128 n (2 oh rows x 56 ow + pad), BK=64, 36 steps x 32 MFMA/wave.
// All staging via global_load_lds(16B); swizzled LDS -> conflict-free reads.
__global__ __launch_bounds__(256) void k_ds(
        const ushort_t* __restrict__ comb, const ushort_t* __restrict__ wds2,
        const float* __restrict__ a2, const float* __restrict__ b2,
        float* __restrict__ out) {
    __shared__ ushort_t lA[128 * 64];   // [oc][64ch], 16 KB, chunk-swizzled
    __shared__ ushort_t lB[128 * 64];   // [n][64ch],  16 KB, chunk-swizzled
    int t = threadIdx.x, lane = t & 63, wave = t >> 6;
    // XCD-aware decode: 4 oc-tiles of one (b,oh-pair) -> same XCD, contiguous
    int g = blockIdx.x;
    int xcd = g & 7, s = g >> 3;        // s in [0,224)
    int octile = s & 3, pl = s >> 2;    // pl in [0,56)
    int pair = xcd * 56 + pl;           // [0,448)
    int bb = pair / 28, ohp = pair % 28;
    int oh0 = ohp * 2, oc0 = octile * 128;
    int mrow = lane & 15, quad = lane >> 4;
    int wm = wave & 1, wn = wave >> 1;
    int ak = mrow & 7;                  // A swizzle key (row&7 == mrow&7)

    f32x4 acc[4][4] = {};
    for (int kt = 0; kt < 36; kt++) {
        int khw = kt >> 2, icc = kt & 3;
        int kh = khw / 3, kw = khw - kh * 3;
        int p = (kw == 1) ? 0 : 1;
        bool zh0 = (oh0 == 0) && (kh == 0);        // r=-1: zero half 0
        int ldsShift = (kw == 0) ? 128 : 0;        // row0 holds w2=-1 zeros
        __syncthreads();
        if (zh0) {
            int4 z = {0, 0, 0, 0};
            *(int4*)(lB + t * 8) = z;
            *(int4*)(lB + 2048 + t * 8) = z;
        }
        if (kw == 0 && t < 16) {                   // zero w2=-1 row, both halves
            int4 z = {0, 0, 0, 0};
            *(int4*)(lB + (t >> 3) * 4096 + (t & 7) * 8) = z;
        }
        // --- A: 16 KB contiguous slab, 4 DMA per wave ---
        const char* asrc = (const char*)wds2
            + ((size_t)kt * 32768 + (size_t)oc0 * 64) * 2 + lane * 16;
#pragma unroll
        for (int i = 0; i < 4; i++) {
            int j = wave * 4 + i;
            gl_lds16(asrc + j * 1024, (char*)lA + j * 1024);
        }
        // --- B: two 7 KB row-slabs, 14 DMA round-robin over waves ---
        for (int j = wave; j < 14; j += 4) {
            int osub = (j >= 7) ? 1 : 0, jj = j - osub * 7;
            if (zh0 && osub == 0) continue;
            int r = 2 * oh0 + 2 * osub + kh - 1;   // 0..111 here
            const char* bsrc = (const char*)comb
                + ((size_t)bb * C_B + (size_t)r * C_H + (size_t)p * C_P
                   + (size_t)icc * C_I) * 2 + jj * 1024 + lane * 16;
            gl_lds16(bsrc, (char*)lB + osub * 8192 + ldsShift + jj * 1024);
        }
        __syncthreads();
        // --- frags + MFMA: wave (wm,wn) computes 64oc x 64n ---
        int bk = (mrow + ((kw == 0) ? 7 : 0)) & 7; // B swizzle key
#pragma unroll
        for (int ks = 0; ks < 2; ks++) {
            bf16x8 af[4], bf[4];
#pragma unroll
            for (int m = 0; m < 4; m++) {
                int row = wm * 64 + m * 16 + mrow;
                int ph = (ks * 4 + quad) ^ ak;
                af[m] = *(const bf16x8*)(lA + row * 64 + ph * 8);
            }
#pragma unroll
            for (int n = 0; n < 4; n++) {
                int nr = wn * 64 + n * 16 + mrow;
                int ph = (ks * 4 + quad) ^ bk;
                bf[n] = *(const bf16x8*)(lB + nr * 64 + ph * 8);
            }
#pragma unroll
            for (int m = 0; m < 4; m++)
#pragma unroll
                for (int n = 0; n < 4; n++)
                    acc[m][n] = __builtin_amdgcn_mfma_f32_16x16x32_bf16(
                        af[m], bf[n], acc[m][n], 0, 0, 0);
        }
    }
    // --- epilogue: BN2 + ReLU; D row=oc (quad*4+r), col=n (mrow) ---
#pragma unroll
    for (int m = 0; m < 4; m++) {
#pragma unroll
        for (int r4 = 0; r4 < 4; r4++) {
            int oc = oc0 + wm * 64 + m * 16 + quad * 4 + r4;
            float al = a2[oc], be = b2[oc];
#pragma unroll
            for (int n = 0; n < 4; n++) {
                int nr = wn * 64 + n * 16 + mrow;
                int osub = nr >> 6, ow = nr & 63;
                if (ow < OWn) {
                    float v = fmaxf(acc[m][n][r4] * al + be, 0.f);
                    out[((size_t)(bb * OCn + oc) * OHn + (oh0 + osub)) * OWn + ow] = v;
                }
            }
        }
    }
}

// ------------------------- launch ------------------------------------------
extern "C" void kernel_launch(void* const* d_in, const int* in_sizes, int n_in,
                              void* d_out, int out_size, void* d_ws, size_t ws_size,
                              hipStream_t stream) {
    const float* x     = (const float*)d_in[0];
    const float* wkg   = (const float*)d_in[1];
    const float* gdw_w = (const float*)d_in[2];
    const float* gdw_b = (const float*)d_in[3];
    const float* gpw_w = (const float*)d_in[4];
    const float* gpw_b = (const float*)d_in[5];
    const float* bn1g  = (const float*)d_in[6];
    const float* bn1b  = (const float*)d_in[7];
    const float* bn1m  = (const float*)d_in[8];
    const float* bn1v  = (const float*)d_in[9];
    const float* dsw   = (const float*)d_in[10];
    const float* dsb   = (const float*)d_in[11];
    const float* bn2g  = (const float*)d_in[12];
    const float* bn2b  = (const float*)d_in[13];
    const float* bn2m  = (const float*)d_in[14];
    const float* bn2v  = (const float*)d_in[15];

    // workspace layout (bytes). Same proven footprint; tbuf slot now unused.
    char* ws = (char*)d_ws;
    float*    pooled = (float*)(ws + 0);           //  2048 f32 (sums)
    float*    kgen   = (float*)(ws + 8192);        // 18432 f32
    float*    a1     = (float*)(ws + 81920);       //  128 f32
    float*    b1     = (float*)(ws + 82432);
    float*    a2     = (float*)(ws + 82944);       //  512 f32
    float*    b2     = (float*)(ws + 84992);
    ushort_t* gpwbf  = (ushort_t*)(ws + 87040);    // 16384 bf16
    ushort_t* wds2   = (ushort_t*)(ws + 119808);   // 36*512*64 bf16 (2.36 MB)
    ushort_t* comb   = (ushort_t*)(ws + 2479104);  // 102,760,448 B
    // xT (NHWC bf16 copy of x) lives in d_out: exactly 102,760,448 B, consumed
    // by k_dwc before k_ds overwrites d_out with the real output.
    ushort_t* xT  = (ushort_t*)d_out;
    float*    out = (float*)d_out;

    k_prep<<<64, 256, 0, stream>>>(gpw_w, gpw_b, bn1g, bn1b, bn1m, bn1v,
                                   dsb, bn2g, bn2b, bn2m, bn2v,
                                   gpwbf, a1, b1, a2, b2, pooled);
    k_wds <<<4608, 256, 0, stream>>>(dsw, wds2);
    k_xt  <<<1792, 256, 0, stream>>>(x, xT, pooled);
    k_kgen<<<72, 256, 0, stream>>>(pooled, wkg, kgen);
    k_dwc <<<dim3(Hh, Bn * 2), 256, 0, stream>>>(xT, kgen, gdw_w, gdw_b,
                                                 gpwbf, a1, b1, comb);
    k_ds  <<<1792, 256, 0, stream>>>(comb, wds2, a2, b2, out);
}